// Round 3
// baseline (135.695 us; speedup 1.0000x reference)
//
#include <hip/hip_runtime.h>
#include <hip/hip_bf16.h>

// HybridLoss: focal + contrastive + 0.1*graph_reg.  N=8192, D=128.
// Contrastive split algebraically:
//   same-label pairs: sum sq = 2*n_c*S_c - 2*||sum_c f||^2  (O(N*D), exact)
//   diff-label pairs: relu(1 - dist)^2 nonzero only if sq<1 -> MFMA Gram +
//     min-scan; exact slow path only if any pair has sq<1 (never for this data).
// fbf stored PRE-SWIZZLED in MFMA fragment order: chunk(g=row/16, c, m=row%16)
// at byte g*4096 + c*256 + m*16 -> wave fragment loads are 1KB contiguous.

#define N_PTS 8192
#define DIM 128

typedef __bf16 bf16x8 __attribute__((ext_vector_type(8)));
typedef float f32x4 __attribute__((ext_vector_type(4)));

// workspace layout (bytes)
#define FBF_OFF   0                            // __bf16[8192*128] = 2 MB (swizzled)
#define SQN_OFF   (N_PTS * DIM * 2)            // float[8192]
#define CPART_OFF (SQN_OFF + N_PTS * 4)        // float[2080*4]
#define FPART_OFF (CPART_OFF + 8320 * 4)       // float[32]
#define GPART_OFF (FPART_OFF + 32 * 4)         // float[256]
#define VPART_OFF (GPART_OFF + 256 * 4)        // float[32*256]
#define DONE_OFF  (VPART_OFF + 32 * 256 * 4)   // unsigned[1]

// ======== fused aux: prep(bf16 swizzle + sqn) / colsum / focal / graph ========
// grid: [0,512) prep, [512,544) colsum, [544,576) focal, [576,832) graph
__global__ __launch_bounds__(256) void aux_kernel(const float* __restrict__ feat,
                                                  const float* __restrict__ preds,
                                                  const float* __restrict__ targets,
                                                  const float* __restrict__ gfeat,
                                                  __bf16* __restrict__ fbf,
                                                  float* __restrict__ sqn,
                                                  float* __restrict__ vpart,
                                                  float* __restrict__ f_part,
                                                  float* __restrict__ g_part,
                                                  unsigned* __restrict__ done_ctr) {
    __shared__ __align__(16) char smem[8192];
    const int bx = blockIdx.x;
    const int tid = threadIdx.x;
    const int w = tid >> 6;
    const int lane = tid & 63;

    if (bx == 0 && tid == 0) *done_ctr = 0;

    if (bx < 512) {
        // ---- prep: 16 rows per block; coalesced read -> LDS -> coalesced write --
        const int g = bx;
        const float4* feat4 = reinterpret_cast<const float4*>(feat);
        const float4 a = feat4[g * 512 + tid * 2];
        const float4 b = feat4[g * 512 + tid * 2 + 1];
        // thread t holds row m=t>>4, chunk c=t&15 (dims 8c..8c+7)
        const int m = tid >> 4, c = tid & 15;
        union { __bf16 h[8]; uint4 u; } pk;
        pk.h[0] = (__bf16)a.x; pk.h[1] = (__bf16)a.y;
        pk.h[2] = (__bf16)a.z; pk.h[3] = (__bf16)a.w;
        pk.h[4] = (__bf16)b.x; pk.h[5] = (__bf16)b.y;
        pk.h[6] = (__bf16)b.z; pk.h[7] = (__bf16)b.w;
        *reinterpret_cast<uint4*>(smem + c * 256 + m * 16) = pk.u;
        float s = a.x * a.x + a.y * a.y + a.z * a.z + a.w * a.w
                + b.x * b.x + b.y * b.y + b.z * b.z + b.w * b.w;
        s += __shfl_down(s, 8); s += __shfl_down(s, 4);
        s += __shfl_down(s, 2); s += __shfl_down(s, 1);
        if (c == 0) sqn[g * 16 + m] = s;
        __syncthreads();
        reinterpret_cast<uint4*>(fbf)[g * 256 + tid] =
            *reinterpret_cast<const uint4*>(smem + tid * 16);
    } else if (bx < 544) {
        // ---- per-class column sums: 256 rows per block, coalesced ----
        const int b = bx - 512;
        const float2* feat2 = reinterpret_cast<const float2*>(feat);
        float2 accA = {0.f, 0.f}, acc1 = {0.f, 0.f};
        int r = b * 256 + w * 64;
        #pragma unroll 4
        for (int i = 0; i < 64; ++i, ++r) {
            const float2 v = feat2[r * 64 + lane];
            const float tr = targets[r];
            accA.x += v.x; accA.y += v.y;
            acc1.x += tr * v.x; acc1.y += tr * v.y;
        }
        float* fA = reinterpret_cast<float*>(smem);          // [4][128]
        float* f1 = reinterpret_cast<float*>(smem + 2048);   // [4][128]
        fA[w * 128 + 2 * lane] = accA.x; fA[w * 128 + 2 * lane + 1] = accA.y;
        f1[w * 128 + 2 * lane] = acc1.x; f1[w * 128 + 2 * lane + 1] = acc1.y;
        __syncthreads();
        if (tid < 128) {
            const int d = tid;
            const float c1 = f1[d] + f1[128 + d] + f1[256 + d] + f1[384 + d];
            const float ca = fA[d] + fA[128 + d] + fA[256 + d] + fA[384 + d];
            vpart[b * 256 + tid] = ca - c1;                  // class 0
        } else {
            const int d = tid - 128;
            vpart[b * 256 + tid] = f1[d] + f1[128 + d] + f1[256 + d] + f1[384 + d];
        }
    } else if (bx < 576) {
        // ---- focal partials ----
        const int b = bx - 544;
        const int i = b * 256 + tid;
        const float p = preds[i], t = targets[i];
        const float bce = fmaxf(p, 0.f) - p * t + log1pf(expf(-fabsf(p)));
        const float pt = expf(-bce);
        const float om = 1.f - pt;
        float v = 0.25f * om * om * bce;
        #pragma unroll
        for (int off = 32; off > 0; off >>= 1) v += __shfl_down(v, off);
        float* red = reinterpret_cast<float*>(smem);
        if (lane == 0) red[w] = v;
        __syncthreads();
        if (tid == 0) f_part[b] = red[0] + red[1] + red[2] + red[3];
    } else {
        // ---- graph regularizer partials ----
        const int b = bx - 576;
        float acc = 0.f;
        #pragma unroll
        for (int it = 0; it < 8; ++it) {
            const int r = b * 4 + w + it * 1024;
            if (r < N_PTS - 1) {
                const float2 a = *reinterpret_cast<const float2*>(gfeat + r * DIM + lane * 2);
                const float2 bb = *reinterpret_cast<const float2*>(gfeat + (r + 1) * DIM + lane * 2);
                const float dx = bb.x - a.x, dy = bb.y - a.y;
                float s = dx * dx + dy * dy;
                #pragma unroll
                for (int off = 32; off > 0; off >>= 1) s += __shfl_down(s, off);
                if (lane == 0) acc += sqrtf(s);
            }
        }
        float* red = reinterpret_cast<float*>(smem);
        if (lane == 0) red[w] = acc;
        __syncthreads();
        if (tid == 0) g_part[b] = red[0] + red[1] + red[2] + red[3];
    }
}

// ================= pair kernel: MFMA Gram + margin min-scan ======================
template<bool DIAG>
__device__ __forceinline__ float scan_min(const f32x4 (&acc)[4][4],
                                          const f32x4 (&sqni)[4], const f32x4 (&ti4)[4],
                                          const float (&sqnj)[4], const float (&tj4)[4],
                                          int wm, int wn, int quad, int m15) {
    float minkey = 1e30f;
    #pragma unroll
    for (int tm = 0; tm < 4; ++tm) {
        #pragma unroll
        for (int tn = 0; tn < 4; ++tn) {
            const int jl = wn * 64 + tn * 16 + m15;
            #pragma unroll
            for (int e = 0; e < 4; ++e) {
                const float sq = sqni[tm][e] + sqnj[tn] - 2.f * acc[tm][tn][e];
                bool excl = (ti4[tm][e] == tj4[tn]);
                if (DIAG) {
                    const int il = wm * 64 + tm * 16 + quad * 4 + e;
                    excl = excl || (jl <= il);
                }
                minkey = fminf(minkey, excl ? 1e30f : sq);
            }
        }
    }
    return minkey;
}

template<bool DIAG>
__device__ __forceinline__ float scan_slow(const f32x4 (&acc)[4][4],
                                           const f32x4 (&sqni)[4], const f32x4 (&ti4)[4],
                                           const float (&sqnj)[4], const float (&tj4)[4],
                                           int wm, int wn, int quad, int m15) {
    float lsum = 0.f;
    #pragma unroll
    for (int tm = 0; tm < 4; ++tm) {
        #pragma unroll
        for (int tn = 0; tn < 4; ++tn) {
            const int jl = wn * 64 + tn * 16 + m15;
            #pragma unroll
            for (int e = 0; e < 4; ++e) {
                const float sq = sqni[tm][e] + sqnj[tn] - 2.f * acc[tm][tn][e];
                bool excl = (ti4[tm][e] == tj4[tn]);
                if (DIAG) {
                    const int il = wm * 64 + tm * 16 + quad * 4 + e;
                    excl = excl || (jl <= il);
                }
                if (!excl && sq < 1.f) {
                    const float d = sqrtf(fmaxf(sq, 0.f));
                    const float m = 1.f - d;
                    lsum += 2.f * m * m;
                }
            }
        }
    }
    return lsum;
}

__global__ __launch_bounds__(256) void pair_kernel(const __bf16* __restrict__ fbf,
                                                   const float* __restrict__ sqn,
                                                   const float* __restrict__ targets,
                                                   float* __restrict__ c_part,
                                                   const float* __restrict__ f_part,
                                                   const float* __restrict__ g_part,
                                                   const float* __restrict__ vpart,
                                                   unsigned* __restrict__ done_ctr,
                                                   float* __restrict__ out) {
    // decode upper-tri block index u -> (bi, bj), bi <= bj
    const int u = blockIdx.x;
    const int v = 2079 - u;
    int k = (int)((sqrtf(8.f * (float)v + 1.f) - 1.f) * 0.5f);
    while ((k + 1) * (k + 2) / 2 <= v) ++k;
    while (k * (k + 1) / 2 > v) --k;
    const int bi = 63 - k;
    const int bj = 63 - (v - k * (k + 1) / 2);

    const int tid = threadIdx.x;
    const int lane = tid & 63;
    const int wv = tid >> 6;
    const int quad = lane >> 4;
    const int m15 = lane & 15;
    const int wm = wv >> 1, wn = wv & 1;
    const int ibase = bi * 128, jbase = bj * 128;

    // fragment loads from pre-swizzled global: 1KB contiguous per wave-load
    const uint4* fp = reinterpret_cast<const uint4*>(fbf);
    const uint4* base_a = fp + (bi * 8 + wm * 4) * 256 + quad * 16 + m15;
    const uint4* base_b = fp + (bj * 8 + wn * 4) * 256 + quad * 16 + m15;
    bf16x8 af[4][4], bfr[4][4];       // [t][ks]
    #pragma unroll
    for (int t = 0; t < 4; ++t)
        #pragma unroll
        for (int ks = 0; ks < 4; ++ks) {
            af[t][ks]  = *reinterpret_cast<const bf16x8*>(base_a + t * 256 + ks * 64);
            bfr[t][ks] = *reinterpret_cast<const bf16x8*>(base_b + t * 256 + ks * 64);
        }

    f32x4 acc[4][4];
    #pragma unroll
    for (int a = 0; a < 4; ++a)
        #pragma unroll
        for (int b = 0; b < 4; ++b) acc[a][b] = (f32x4){0.f, 0.f, 0.f, 0.f};

    #pragma unroll
    for (int ks = 0; ks < 4; ++ks)
        #pragma unroll
        for (int tm = 0; tm < 4; ++tm)
            #pragma unroll
            for (int tn = 0; tn < 4; ++tn)
                acc[tm][tn] = __builtin_amdgcn_mfma_f32_16x16x32_bf16(
                    af[tm][ks], bfr[tn][ks], acc[tm][tn], 0, 0, 0);

    // epilogue inputs
    f32x4 sqni[4], ti4[4];
    float sqnj[4], tj4[4];
    #pragma unroll
    for (int tm = 0; tm < 4; ++tm) {
        const int i0 = wm * 64 + tm * 16 + quad * 4;
        sqni[tm] = *reinterpret_cast<const f32x4*>(sqn + ibase + i0);
        ti4[tm]  = *reinterpret_cast<const f32x4*>(targets + ibase + i0);
    }
    #pragma unroll
    for (int tn = 0; tn < 4; ++tn) {
        const int jl = wn * 64 + tn * 16 + m15;
        sqnj[tn] = sqn[jbase + jl];
        tj4[tn]  = targets[jbase + jl];
    }

    const bool diag = (bi == bj);
    const float minkey = diag
        ? scan_min<true >(acc, sqni, ti4, sqnj, tj4, wm, wn, quad, m15)
        : scan_min<false>(acc, sqni, ti4, sqnj, tj4, wm, wn, quad, m15);

    float lsum = 0.f;
    if (minkey < 1.f)
        lsum = diag
            ? scan_slow<true >(acc, sqni, ti4, sqnj, tj4, wm, wn, quad, m15)
            : scan_slow<false>(acc, sqni, ti4, sqnj, tj4, wm, wn, quad, m15);

    float wsum = 0.f;
    if (__any(minkey < 1.f)) {
        #pragma unroll
        for (int off = 32; off > 0; off >>= 1) lsum += __shfl_down(lsum, off);
        wsum = lsum;
    }
    if (lane == 0) c_part[u * 4 + wv] = wsum;

    // -------- last-block-done: fused finalize --------
    __shared__ int amLast;
    __syncthreads();
    if (tid == 0) {
        __threadfence();
        amLast = (atomicAdd(done_ctr, 1u) == 2079u);
    }
    __syncthreads();
    if (!amLast) return;
    __threadfence();

    __shared__ float red[32];
    const int w = wv;
    float c = 0.f;
    for (int i = tid; i < 8320; i += 256) c += c_part[i];
    float f = (tid < 32) ? f_part[tid] : 0.f;
    float g = g_part[tid];

    float V = 0.f;
    #pragma unroll 8
    for (int b = 0; b < 32; ++b) V += vpart[b * 256 + tid];
    float vsq = V * V;                 // tid<128: class 0; else class 1

    float stot = 0.f, s1 = 0.f, n1 = 0.f;
    for (int i = tid; i < N_PTS; i += 256) {
        const float s = sqn[i], t = targets[i];
        stot += s; s1 += t * s; n1 += t;
    }

    #pragma unroll
    for (int off = 32; off > 0; off >>= 1) {
        c += __shfl_down(c, off);
        f += __shfl_down(f, off);
        g += __shfl_down(g, off);
        vsq  += __shfl_down(vsq, off);
        stot += __shfl_down(stot, off);
        s1   += __shfl_down(s1, off);
        n1   += __shfl_down(n1, off);
    }
    if (lane == 0) {
        red[w] = c; red[4 + w] = f; red[8 + w] = g;
        red[12 + w] = vsq; red[16 + w] = stot; red[20 + w] = s1; red[24 + w] = n1;
    }
    __syncthreads();
    if (tid == 0) {
        const double cs = (double)red[0] + red[1] + red[2] + red[3];
        const double fs = (double)red[4] + red[5] + red[6] + red[7];
        const double gs = (double)red[8] + red[9] + red[10] + red[11];
        const double v0sq = (double)red[12] + red[13];   // waves 0,1 = class 0
        const double v1sq = (double)red[14] + red[15];
        const double st = (double)red[16] + red[17] + red[18] + red[19];
        const double s1s = (double)red[20] + red[21] + red[22] + red[23];
        const double n1s = (double)red[24] + red[25] + red[26] + red[27];
        const double n0s = (double)N_PTS - n1s;
        const double s0s = st - s1s;
        const double same = 2.0 * (n0s * s0s - v0sq) + 2.0 * (n1s * s1s - v1sq);
        out[0] = (float)((cs + same) / ((double)N_PTS * N_PTS)
                         + fs / N_PTS + 0.1 * (gs / (N_PTS - 1)));
    }
}

extern "C" void kernel_launch(void* const* d_in, const int* in_sizes, int n_in,
                              void* d_out, int out_size, void* d_ws, size_t ws_size,
                              hipStream_t stream) {
    const float* preds    = (const float*)d_in[0];
    const float* targets  = (const float*)d_in[1];
    const float* features = (const float*)d_in[2];
    const float* gfeat    = (const float*)d_in[3];
    char* ws = (char*)d_ws;
    __bf16* fbf   = (__bf16*)(ws + FBF_OFF);
    float* sqn    = (float*)(ws + SQN_OFF);
    float* c_part = (float*)(ws + CPART_OFF);
    float* f_part = (float*)(ws + FPART_OFF);
    float* g_part = (float*)(ws + GPART_OFF);
    float* vpart  = (float*)(ws + VPART_OFF);
    unsigned* done = (unsigned*)(ws + DONE_OFF);
    float* out = (float*)d_out;

    aux_kernel<<<832, 256, 0, stream>>>(features, preds, targets, gfeat,
                                        fbf, sqn, vpart, f_part, g_part, done);
    pair_kernel<<<2080, 256, 0, stream>>>(fbf, sqn, targets, c_part,
                                          f_part, g_part, vpart, done, out);
}

// Round 4
// 111.670 us; speedup vs baseline: 1.2151x; 1.2151x over previous
//
#include <hip/hip_runtime.h>
#include <hip/hip_bf16.h>

// HybridLoss: focal + contrastive + 0.1*graph_reg.  N=8192, D=128.
// Contrastive split algebraically:
//   same-label pairs: sum sq = 2*n_c*S_c - 2*||sum_c f||^2  (O(N*D), exact)
//   diff-label pairs: relu(1 - dist)^2 nonzero only if sq<1 -> MFMA Gram +
//     cheap unconditional min-scan; exact (label/triangle-aware) slow path only
//     when min sq < 2 in a wave's sub-tile (only diagonal self-pairs here).
// fbf stored PRE-SWIZZLED in MFMA fragment order: chunk(g=row/16, c, m=row%16)
// at byte g*4096 + c*256 + m*16 -> wave fragment loads are 1KB contiguous.
// NOTE: no __threadfence / fused finalize — per-block device-scope release
// fences (buffer_wbl2) thrashed L2 in round 3 (68us vs ~10us model).

#define N_PTS 8192
#define DIM 128

typedef __bf16 bf16x8 __attribute__((ext_vector_type(8)));
typedef float f32x4 __attribute__((ext_vector_type(4)));

// workspace layout (bytes)
#define FBF_OFF   0                            // __bf16[8192*128] = 2 MB (swizzled)
#define SQN_OFF   (N_PTS * DIM * 2)            // float[8192]
#define CPART_OFF (SQN_OFF + N_PTS * 4)        // float[2080*4]
#define FPART_OFF (CPART_OFF + 8320 * 4)       // float[32]
#define GPART_OFF (FPART_OFF + 32 * 4)         // float[256]
#define VPART_OFF (GPART_OFF + 256 * 4)        // float[32*256]

// ======== fused aux: prep(bf16 swizzle + sqn) / colsum / focal / graph ========
// grid: [0,512) prep, [512,544) colsum, [544,576) focal, [576,832) graph
__global__ __launch_bounds__(256) void aux_kernel(const float* __restrict__ feat,
                                                  const float* __restrict__ preds,
                                                  const float* __restrict__ targets,
                                                  const float* __restrict__ gfeat,
                                                  __bf16* __restrict__ fbf,
                                                  float* __restrict__ sqn,
                                                  float* __restrict__ vpart,
                                                  float* __restrict__ f_part,
                                                  float* __restrict__ g_part) {
    __shared__ __align__(16) char smem[8192];
    const int bx = blockIdx.x;
    const int tid = threadIdx.x;
    const int w = tid >> 6;
    const int lane = tid & 63;

    if (bx < 512) {
        // ---- prep: 16 rows per block; coalesced read -> LDS -> coalesced write --
        const int g = bx;
        const float4* feat4 = reinterpret_cast<const float4*>(feat);
        const float4 a = feat4[g * 512 + tid * 2];
        const float4 b = feat4[g * 512 + tid * 2 + 1];
        // thread t holds row m=t>>4, chunk c=t&15 (dims 8c..8c+7)
        const int m = tid >> 4, c = tid & 15;
        union { __bf16 h[8]; uint4 u; } pk;
        pk.h[0] = (__bf16)a.x; pk.h[1] = (__bf16)a.y;
        pk.h[2] = (__bf16)a.z; pk.h[3] = (__bf16)a.w;
        pk.h[4] = (__bf16)b.x; pk.h[5] = (__bf16)b.y;
        pk.h[6] = (__bf16)b.z; pk.h[7] = (__bf16)b.w;
        *reinterpret_cast<uint4*>(smem + c * 256 + m * 16) = pk.u;
        float s = a.x * a.x + a.y * a.y + a.z * a.z + a.w * a.w
                + b.x * b.x + b.y * b.y + b.z * b.z + b.w * b.w;
        s += __shfl_down(s, 8); s += __shfl_down(s, 4);
        s += __shfl_down(s, 2); s += __shfl_down(s, 1);
        if (c == 0) sqn[g * 16 + m] = s;
        __syncthreads();
        reinterpret_cast<uint4*>(fbf)[g * 256 + tid] =
            *reinterpret_cast<const uint4*>(smem + tid * 16);
    } else if (bx < 544) {
        // ---- per-class column sums: 256 rows per block, coalesced ----
        const int b = bx - 512;
        const float2* feat2 = reinterpret_cast<const float2*>(feat);
        float2 accA = {0.f, 0.f}, acc1 = {0.f, 0.f};
        int r = b * 256 + w * 64;
        #pragma unroll 4
        for (int i = 0; i < 64; ++i, ++r) {
            const float2 v = feat2[r * 64 + lane];
            const float tr = targets[r];
            accA.x += v.x; accA.y += v.y;
            acc1.x += tr * v.x; acc1.y += tr * v.y;
        }
        float* fA = reinterpret_cast<float*>(smem);          // [4][128]
        float* f1 = reinterpret_cast<float*>(smem + 2048);   // [4][128]
        fA[w * 128 + 2 * lane] = accA.x; fA[w * 128 + 2 * lane + 1] = accA.y;
        f1[w * 128 + 2 * lane] = acc1.x; f1[w * 128 + 2 * lane + 1] = acc1.y;
        __syncthreads();
        if (tid < 128) {
            const int d = tid;
            const float c1 = f1[d] + f1[128 + d] + f1[256 + d] + f1[384 + d];
            const float ca = fA[d] + fA[128 + d] + fA[256 + d] + fA[384 + d];
            vpart[b * 256 + tid] = ca - c1;                  // class 0
        } else {
            const int d = tid - 128;
            vpart[b * 256 + tid] = f1[d] + f1[128 + d] + f1[256 + d] + f1[384 + d];
        }
    } else if (bx < 576) {
        // ---- focal partials ----
        const int b = bx - 544;
        const int i = b * 256 + tid;
        const float p = preds[i], t = targets[i];
        const float bce = fmaxf(p, 0.f) - p * t + log1pf(expf(-fabsf(p)));
        const float pt = expf(-bce);
        const float om = 1.f - pt;
        float v = 0.25f * om * om * bce;
        #pragma unroll
        for (int off = 32; off > 0; off >>= 1) v += __shfl_down(v, off);
        float* red = reinterpret_cast<float*>(smem);
        if (lane == 0) red[w] = v;
        __syncthreads();
        if (tid == 0) f_part[b] = red[0] + red[1] + red[2] + red[3];
    } else {
        // ---- graph regularizer partials ----
        const int b = bx - 576;
        float acc = 0.f;
        #pragma unroll
        for (int it = 0; it < 8; ++it) {
            const int r = b * 4 + w + it * 1024;
            if (r < N_PTS - 1) {
                const float2 a = *reinterpret_cast<const float2*>(gfeat + r * DIM + lane * 2);
                const float2 bb = *reinterpret_cast<const float2*>(gfeat + (r + 1) * DIM + lane * 2);
                const float dx = bb.x - a.x, dy = bb.y - a.y;
                float s = dx * dx + dy * dy;
                #pragma unroll
                for (int off = 32; off > 0; off >>= 1) s += __shfl_down(s, off);
                if (lane == 0) acc += sqrtf(s);
            }
        }
        float* red = reinterpret_cast<float*>(smem);
        if (lane == 0) red[w] = acc;
        __syncthreads();
        if (tid == 0) g_part[b] = red[0] + red[1] + red[2] + red[3];
    }
}

// ================= pair kernel: MFMA Gram + margin min-scan ======================
// exact slow path (runs only when a lane's min sq < 2: diagonal self-pairs here)
template<bool DIAG>
__device__ __forceinline__ float scan_slow(const f32x4 (&acc)[4][4],
                                           const f32x4 (&sqni)[4], const f32x4 (&ti4)[4],
                                           const float (&sqnj)[4], const float (&tj4)[4],
                                           int wm, int wn, int quad, int m15) {
    float lsum = 0.f;
    #pragma unroll
    for (int tm = 0; tm < 4; ++tm) {
        #pragma unroll
        for (int tn = 0; tn < 4; ++tn) {
            const int jl = wn * 64 + tn * 16 + m15;
            #pragma unroll
            for (int e = 0; e < 4; ++e) {
                const float sq = sqni[tm][e] + sqnj[tn] - 2.f * acc[tm][tn][e];
                bool excl = (ti4[tm][e] == tj4[tn]);
                if (DIAG) {
                    const int il = wm * 64 + tm * 16 + quad * 4 + e;
                    excl = excl || (jl <= il);
                }
                if (!excl && sq < 1.f) {
                    const float d = sqrtf(fmaxf(sq, 0.f));
                    const float m = 1.f - d;
                    lsum += 2.f * m * m;     // off-diag block or strict-upper: weight 2
                }
            }
        }
    }
    return lsum;
}

__global__ __launch_bounds__(256) void pair_kernel(const __bf16* __restrict__ fbf,
                                                   const float* __restrict__ sqn,
                                                   const float* __restrict__ targets,
                                                   float* __restrict__ c_part) {
    // decode upper-tri block index u -> (bi, bj), bi <= bj
    const int u = blockIdx.x;
    const int v = 2079 - u;
    int k = (int)((sqrtf(8.f * (float)v + 1.f) - 1.f) * 0.5f);
    while ((k + 1) * (k + 2) / 2 <= v) ++k;
    while (k * (k + 1) / 2 > v) --k;
    const int bi = 63 - k;
    const int bj = 63 - (v - k * (k + 1) / 2);

    const int tid = threadIdx.x;
    const int lane = tid & 63;
    const int wv = tid >> 6;
    const int quad = lane >> 4;
    const int m15 = lane & 15;
    const int wm = wv >> 1, wn = wv & 1;
    const int ibase = bi * 128, jbase = bj * 128;

    // fragment loads from pre-swizzled global: 1KB contiguous per wave-load
    const uint4* fp = reinterpret_cast<const uint4*>(fbf);
    const uint4* base_a = fp + (bi * 8 + wm * 4) * 256 + quad * 16 + m15;
    const uint4* base_b = fp + (bj * 8 + wn * 4) * 256 + quad * 16 + m15;
    bf16x8 af[4][4], bfr[4][4];       // [t][ks]
    #pragma unroll
    for (int t = 0; t < 4; ++t)
        #pragma unroll
        for (int ks = 0; ks < 4; ++ks) {
            af[t][ks]  = *reinterpret_cast<const bf16x8*>(base_a + t * 256 + ks * 64);
            bfr[t][ks] = *reinterpret_cast<const bf16x8*>(base_b + t * 256 + ks * 64);
        }

    f32x4 acc[4][4];
    #pragma unroll
    for (int a = 0; a < 4; ++a)
        #pragma unroll
        for (int b = 0; b < 4; ++b) acc[a][b] = (f32x4){0.f, 0.f, 0.f, 0.f};

    #pragma unroll
    for (int ks = 0; ks < 4; ++ks)
        #pragma unroll
        for (int tm = 0; tm < 4; ++tm)
            #pragma unroll
            for (int tn = 0; tn < 4; ++tn)
                acc[tm][tn] = __builtin_amdgcn_mfma_f32_16x16x32_bf16(
                    af[tm][ks], bfr[tn][ks], acc[tm][tn], 0, 0, 0);

    // epilogue inputs
    f32x4 sqni[4], ti4[4];
    float sqnj[4], tj4[4];
    #pragma unroll
    for (int tm = 0; tm < 4; ++tm) {
        const int i0 = wm * 64 + tm * 16 + quad * 4;
        sqni[tm] = *reinterpret_cast<const f32x4*>(sqn + ibase + i0);
        ti4[tm]  = *reinterpret_cast<const f32x4*>(targets + ibase + i0);
    }
    #pragma unroll
    for (int tn = 0; tn < 4; ++tn) {
        const int jl = wn * 64 + tn * 16 + m15;
        sqnj[tn] = sqn[jbase + jl];
        tj4[tn]  = targets[jbase + jl];
    }

    // unconditional min-scan (3 VALU/elem): min sq over ALL pairs in sub-tile.
    // Any real margin hit (sq<1) is caught; self-pairs (sq~0) trigger the exact
    // slow path on diagonal blocks only.
    float minkey = 1e30f;
    #pragma unroll
    for (int tm = 0; tm < 4; ++tm)
        #pragma unroll
        for (int tn = 0; tn < 4; ++tn)
            #pragma unroll
            for (int e = 0; e < 4; ++e) {
                const float sq = fmaf(-2.f, acc[tm][tn][e], sqni[tm][e]) + sqnj[tn];
                minkey = fminf(minkey, sq);
            }

    const bool diag = (bi == bj);
    float lsum = 0.f;
    if (minkey < 2.f)
        lsum = diag
            ? scan_slow<true >(acc, sqni, ti4, sqnj, tj4, wm, wn, quad, m15)
            : scan_slow<false>(acc, sqni, ti4, sqnj, tj4, wm, wn, quad, m15);

    #pragma unroll
    for (int off = 32; off > 0; off >>= 1) lsum += __shfl_down(lsum, off);
    if (lane == 0) c_part[u * 4 + wv] = lsum;
}

// ================= finalize =====================================================
__global__ __launch_bounds__(256) void finalize_kernel(const float* __restrict__ c_part,
                                                       const float* __restrict__ f_part,
                                                       const float* __restrict__ g_part,
                                                       const float* __restrict__ vpart,
                                                       const float* __restrict__ sqn,
                                                       const float* __restrict__ targets,
                                                       float* __restrict__ out) {
    __shared__ float red[32];
    const int tid = threadIdx.x;
    const int w = tid >> 6, lane = tid & 63;

    float c = 0.f;
    for (int i = tid; i < 8320; i += 256) c += c_part[i];
    float f = (tid < 32) ? f_part[tid] : 0.f;
    float g = g_part[tid];

    float V = 0.f;
    #pragma unroll 8
    for (int b = 0; b < 32; ++b) V += vpart[b * 256 + tid];
    float vsq = V * V;                 // tid<128: class 0; else class 1

    float stot = 0.f, s1 = 0.f, n1 = 0.f;
    for (int i = tid; i < N_PTS; i += 256) {
        const float s = sqn[i], t = targets[i];
        stot += s; s1 += t * s; n1 += t;
    }

    #pragma unroll
    for (int off = 32; off > 0; off >>= 1) {
        c += __shfl_down(c, off);
        f += __shfl_down(f, off);
        g += __shfl_down(g, off);
        vsq  += __shfl_down(vsq, off);
        stot += __shfl_down(stot, off);
        s1   += __shfl_down(s1, off);
        n1   += __shfl_down(n1, off);
    }
    if (lane == 0) {
        red[w] = c; red[4 + w] = f; red[8 + w] = g;
        red[12 + w] = vsq; red[16 + w] = stot; red[20 + w] = s1; red[24 + w] = n1;
    }
    __syncthreads();
    if (tid == 0) {
        const double cs = (double)red[0] + red[1] + red[2] + red[3];
        const double fs = (double)red[4] + red[5] + red[6] + red[7];
        const double gs = (double)red[8] + red[9] + red[10] + red[11];
        const double v0sq = (double)red[12] + red[13];   // waves 0,1 = class 0
        const double v1sq = (double)red[14] + red[15];
        const double st = (double)red[16] + red[17] + red[18] + red[19];
        const double s1s = (double)red[20] + red[21] + red[22] + red[23];
        const double n1s = (double)red[24] + red[25] + red[26] + red[27];
        const double n0s = (double)N_PTS - n1s;
        const double s0s = st - s1s;
        const double same = 2.0 * (n0s * s0s - v0sq) + 2.0 * (n1s * s1s - v1sq);
        out[0] = (float)((cs + same) / ((double)N_PTS * N_PTS)
                         + fs / N_PTS + 0.1 * (gs / (N_PTS - 1)));
    }
}

extern "C" void kernel_launch(void* const* d_in, const int* in_sizes, int n_in,
                              void* d_out, int out_size, void* d_ws, size_t ws_size,
                              hipStream_t stream) {
    const float* preds    = (const float*)d_in[0];
    const float* targets  = (const float*)d_in[1];
    const float* features = (const float*)d_in[2];
    const float* gfeat    = (const float*)d_in[3];
    char* ws = (char*)d_ws;
    __bf16* fbf   = (__bf16*)(ws + FBF_OFF);
    float* sqn    = (float*)(ws + SQN_OFF);
    float* c_part = (float*)(ws + CPART_OFF);
    float* f_part = (float*)(ws + FPART_OFF);
    float* g_part = (float*)(ws + GPART_OFF);
    float* vpart  = (float*)(ws + VPART_OFF);
    float* out = (float*)d_out;

    aux_kernel<<<832, 256, 0, stream>>>(features, preds, targets, gfeat,
                                        fbf, sqn, vpart, f_part, g_part);
    pair_kernel<<<2080, 256, 0, stream>>>(fbf, sqn, targets, c_part);
    finalize_kernel<<<1, 256, 0, stream>>>(c_part, f_part, g_part, vpart, sqn, targets, out);
}

// Round 5
// 102.869 us; speedup vs baseline: 1.3191x; 1.0855x over previous
//
#include <hip/hip_runtime.h>
#include <hip/hip_bf16.h>

// HybridLoss: focal + contrastive + 0.1*graph_reg.  N=8192, D=128.
// Contrastive split algebraically:
//   same-label pairs: sum sq = 2*n_c*S_c - 2*||sum_c f||^2  (O(N*D), exact)
//   diff-label pairs: relu(1 - dist)^2 nonzero only if sq<1.
// Screen: sq >= ||d[0:24]||^2 (provable lower bound). Augmented bf16 rows
//   A=[-2f0..-2f23, sqn24, 1, 0x6], B=[f0..f23, 1, sqn24, 0x6] make one
//   K=32 MFMA emit sq24 directly. Wave-min sq24 >= 2 (bf16 slack) => skip.
//   Else exact full-Gram slow path (diag self-pairs always trigger).
// fbf + screen copies PRE-SWIZZLED in MFMA fragment order:
//   chunk(g=row/16, c, m=row%16) at g*CH*256 + c*256 + m*16 (CH=16 full, 4 screen).
// NOTE: no __threadfence / fused finalize — per-block device-scope release
// fences (buffer_wbl2) thrashed L2 in round 3 (68us vs ~10us model).

#define N_PTS 8192
#define DIM 128

typedef __bf16 bf16x8 __attribute__((ext_vector_type(8)));
typedef float f32x4 __attribute__((ext_vector_type(4)));

// workspace layout (bytes)
#define FBF_OFF   0                            // __bf16[8192*128] = 2 MB (swizzled)
#define SQN_OFF   2097152                      // float[8192]
#define CPART_OFF 2129920                      // float[2080*4]
#define FPART_OFF 2163200                      // float[32]
#define GPART_OFF 2163328                      // float[256]
#define VPART_OFF 2164352                      // float[32*256]
#define ASCR_OFF  2197120                      // __bf16[8192*32] = 512 KB (screen A)
#define BSCR_OFF  2721408                      // __bf16[8192*32] = 512 KB (screen B)

// ======== fused aux: prep(bf16 swizzle + screen + sqn) / colsum / focal / graph ==
// grid: [0,512) prep, [512,544) colsum, [544,576) focal, [576,832) graph
__global__ __launch_bounds__(256) void aux_kernel(const float* __restrict__ feat,
                                                  const float* __restrict__ preds,
                                                  const float* __restrict__ targets,
                                                  const float* __restrict__ gfeat,
                                                  __bf16* __restrict__ fbf,
                                                  __bf16* __restrict__ ascr,
                                                  __bf16* __restrict__ bscr,
                                                  float* __restrict__ sqn,
                                                  float* __restrict__ vpart,
                                                  float* __restrict__ f_part,
                                                  float* __restrict__ g_part) {
    __shared__ __align__(16) char smem[8192];
    const int bx = blockIdx.x;
    const int tid = threadIdx.x;
    const int w = tid >> 6;
    const int lane = tid & 63;

    if (bx < 512) {
        // ---- prep: 16 rows/block; full-F staging + screen copies + sqn ----
        // smem: [0,4K) F-chunks, [4K,5K) A-screen, [5K,6K) B-screen, [6K,7K) S[256]
        const int g = bx;
        const float4* feat4 = reinterpret_cast<const float4*>(feat);
        const float4 a = feat4[g * 512 + tid * 2];
        const float4 b = feat4[g * 512 + tid * 2 + 1];
        const int m = tid >> 4, c = tid & 15;     // row m, chunk c (dims 8c..8c+7)
        union { __bf16 h[8]; uint4 u; } pk;
        pk.h[0] = (__bf16)a.x; pk.h[1] = (__bf16)a.y;
        pk.h[2] = (__bf16)a.z; pk.h[3] = (__bf16)a.w;
        pk.h[4] = (__bf16)b.x; pk.h[5] = (__bf16)b.y;
        pk.h[6] = (__bf16)b.z; pk.h[7] = (__bf16)b.w;
        *reinterpret_cast<uint4*>(smem + c * 256 + m * 16) = pk.u;
        if (c < 3) {
            union { __bf16 h[8]; uint4 u; } pa;
            pa.h[0] = (__bf16)(-2.f * a.x); pa.h[1] = (__bf16)(-2.f * a.y);
            pa.h[2] = (__bf16)(-2.f * a.z); pa.h[3] = (__bf16)(-2.f * a.w);
            pa.h[4] = (__bf16)(-2.f * b.x); pa.h[5] = (__bf16)(-2.f * b.y);
            pa.h[6] = (__bf16)(-2.f * b.z); pa.h[7] = (__bf16)(-2.f * b.w);
            *reinterpret_cast<uint4*>(smem + 4096 + c * 256 + m * 16) = pa.u;
            *reinterpret_cast<uint4*>(smem + 5120 + c * 256 + m * 16) = pk.u;
        }
        const float s = a.x * a.x + a.y * a.y + a.z * a.z + a.w * a.w
                      + b.x * b.x + b.y * b.y + b.z * b.z + b.w * b.w;
        reinterpret_cast<float*>(smem + 6144)[m * 16 + c] = s;
        __syncthreads();
        if (c == 3) {
            const float* S = reinterpret_cast<const float*>(smem + 6144);
            const float sq24 = S[m * 16] + S[m * 16 + 1] + S[m * 16 + 2];
            union { __bf16 h[8]; uint4 u; } pa, pb;
            #pragma unroll
            for (int k = 0; k < 8; ++k) { pa.h[k] = (__bf16)0.f; pb.h[k] = (__bf16)0.f; }
            pa.h[0] = (__bf16)sq24; pa.h[1] = (__bf16)1.f;   // A: d24=sqn24, d25=1
            pb.h[0] = (__bf16)1.f;  pb.h[1] = (__bf16)sq24;  // B: d24=1, d25=sqn24
            *reinterpret_cast<uint4*>(smem + 4096 + 3 * 256 + m * 16) = pa.u;
            *reinterpret_cast<uint4*>(smem + 5120 + 3 * 256 + m * 16) = pb.u;
        }
        if (c == 0) {
            const float* S = reinterpret_cast<const float*>(smem + 6144);
            float t = 0.f;
            #pragma unroll
            for (int k = 0; k < 16; ++k) t += S[m * 16 + k];
            sqn[g * 16 + m] = t;
        }
        __syncthreads();
        reinterpret_cast<uint4*>(fbf)[g * 256 + tid] =
            *reinterpret_cast<const uint4*>(smem + tid * 16);
        if (tid < 64)
            reinterpret_cast<uint4*>(ascr)[g * 64 + tid] =
                *reinterpret_cast<const uint4*>(smem + 4096 + tid * 16);
        else if (tid < 128)
            reinterpret_cast<uint4*>(bscr)[g * 64 + (tid - 64)] =
                *reinterpret_cast<const uint4*>(smem + 5120 + (tid - 64) * 16);
    } else if (bx < 544) {
        // ---- per-class column sums: 256 rows per block, coalesced ----
        const int b = bx - 512;
        const float2* feat2 = reinterpret_cast<const float2*>(feat);
        float2 accA = {0.f, 0.f}, acc1 = {0.f, 0.f};
        int r = b * 256 + w * 64;
        #pragma unroll 4
        for (int i = 0; i < 64; ++i, ++r) {
            const float2 v = feat2[r * 64 + lane];
            const float tr = targets[r];
            accA.x += v.x; accA.y += v.y;
            acc1.x += tr * v.x; acc1.y += tr * v.y;
        }
        float* fA = reinterpret_cast<float*>(smem);          // [4][128]
        float* f1 = reinterpret_cast<float*>(smem + 2048);   // [4][128]
        fA[w * 128 + 2 * lane] = accA.x; fA[w * 128 + 2 * lane + 1] = accA.y;
        f1[w * 128 + 2 * lane] = acc1.x; f1[w * 128 + 2 * lane + 1] = acc1.y;
        __syncthreads();
        if (tid < 128) {
            const int d = tid;
            const float c1 = f1[d] + f1[128 + d] + f1[256 + d] + f1[384 + d];
            const float ca = fA[d] + fA[128 + d] + fA[256 + d] + fA[384 + d];
            vpart[b * 256 + tid] = ca - c1;                  // class 0
        } else {
            const int d = tid - 128;
            vpart[b * 256 + tid] = f1[d] + f1[128 + d] + f1[256 + d] + f1[384 + d];
        }
    } else if (bx < 576) {
        // ---- focal partials ----
        const int b = bx - 544;
        const int i = b * 256 + tid;
        const float p = preds[i], t = targets[i];
        const float bce = fmaxf(p, 0.f) - p * t + log1pf(expf(-fabsf(p)));
        const float pt = expf(-bce);
        const float om = 1.f - pt;
        float v = 0.25f * om * om * bce;
        #pragma unroll
        for (int off = 32; off > 0; off >>= 1) v += __shfl_down(v, off);
        float* red = reinterpret_cast<float*>(smem);
        if (lane == 0) red[w] = v;
        __syncthreads();
        if (tid == 0) f_part[b] = red[0] + red[1] + red[2] + red[3];
    } else {
        // ---- graph regularizer partials ----
        const int b = bx - 576;
        float acc = 0.f;
        #pragma unroll
        for (int it = 0; it < 8; ++it) {
            const int r = b * 4 + w + it * 1024;
            if (r < N_PTS - 1) {
                const float2 a = *reinterpret_cast<const float2*>(gfeat + r * DIM + lane * 2);
                const float2 bb = *reinterpret_cast<const float2*>(gfeat + (r + 1) * DIM + lane * 2);
                const float dx = bb.x - a.x, dy = bb.y - a.y;
                float s = dx * dx + dy * dy;
                #pragma unroll
                for (int off = 32; off > 0; off >>= 1) s += __shfl_down(s, off);
                if (lane == 0) acc += sqrtf(s);
            }
        }
        float* red = reinterpret_cast<float*>(smem);
        if (lane == 0) red[w] = acc;
        __syncthreads();
        if (tid == 0) g_part[b] = red[0] + red[1] + red[2] + red[3];
    }
}

// ================= pair kernel: screen MFMA, exact slow path on trigger ==========
template<bool DIAG>
__device__ __forceinline__ float scan_slow(const f32x4 (&acc)[4][4],
                                           const f32x4 (&sqni)[4], const f32x4 (&ti4)[4],
                                           const float (&sqnj)[4], const float (&tj4)[4],
                                           int wm, int wn, int quad, int m15) {
    float lsum = 0.f;
    #pragma unroll
    for (int tm = 0; tm < 4; ++tm) {
        #pragma unroll
        for (int tn = 0; tn < 4; ++tn) {
            const int jl = wn * 64 + tn * 16 + m15;
            #pragma unroll
            for (int e = 0; e < 4; ++e) {
                const float sq = sqni[tm][e] + sqnj[tn] - 2.f * acc[tm][tn][e];
                bool excl = (ti4[tm][e] == tj4[tn]);
                if (DIAG) {
                    const int il = wm * 64 + tm * 16 + quad * 4 + e;
                    excl = excl || (jl <= il);
                }
                if (!excl && sq < 1.f) {
                    const float d = sqrtf(fmaxf(sq, 0.f));
                    const float m = 1.f - d;
                    lsum += 2.f * m * m;     // off-diag block or strict-upper: weight 2
                }
            }
        }
    }
    return lsum;
}

__global__ __launch_bounds__(256, 4) void pair_kernel(const __bf16* __restrict__ fbf,
                                                      const __bf16* __restrict__ ascr,
                                                      const __bf16* __restrict__ bscr,
                                                      const float* __restrict__ sqn,
                                                      const float* __restrict__ targets,
                                                      float* __restrict__ c_part) {
    // decode upper-tri block index u -> (bi, bj), bi <= bj
    const int u = blockIdx.x;
    const int v = 2079 - u;
    int k = (int)((sqrtf(8.f * (float)v + 1.f) - 1.f) * 0.5f);
    while ((k + 1) * (k + 2) / 2 <= v) ++k;
    while (k * (k + 1) / 2 > v) --k;
    const int bi = 63 - k;
    const int bj = 63 - (v - k * (k + 1) / 2);

    const int tid = threadIdx.x;
    const int lane = tid & 63;
    const int wv = tid >> 6;
    const int quad = lane >> 4;
    const int m15 = lane & 15;
    const int wm = wv >> 1, wn = wv & 1;
    const int ibase = bi * 128, jbase = bj * 128;

    // ---- screen: one K=32 MFMA per 16x16 tile emits sq24 directly ----
    const uint4* aS = reinterpret_cast<const uint4*>(ascr);
    const uint4* bS = reinterpret_cast<const uint4*>(bscr);
    const int gA = bi * 8 + wm * 4, gB = bj * 8 + wn * 4;
    bf16x8 afs[4], bfs[4];
    #pragma unroll
    for (int t = 0; t < 4; ++t) {
        afs[t] = *reinterpret_cast<const bf16x8*>(aS + (gA + t) * 64 + quad * 16 + m15);
        bfs[t] = *reinterpret_cast<const bf16x8*>(bS + (gB + t) * 64 + quad * 16 + m15);
    }
    f32x4 acc[4][4];
    #pragma unroll
    for (int a = 0; a < 4; ++a)
        #pragma unroll
        for (int b = 0; b < 4; ++b) acc[a][b] = (f32x4){0.f, 0.f, 0.f, 0.f};
    #pragma unroll
    for (int tm = 0; tm < 4; ++tm)
        #pragma unroll
        for (int tn = 0; tn < 4; ++tn)
            acc[tm][tn] = __builtin_amdgcn_mfma_f32_16x16x32_bf16(
                afs[tm], bfs[tn], acc[tm][tn], 0, 0, 0);

    float minl = 1e30f;
    #pragma unroll
    for (int tm = 0; tm < 4; ++tm)
        #pragma unroll
        for (int tn = 0; tn < 4; ++tn)
            #pragma unroll
            for (int e = 0; e < 4; ++e)
                minl = fminf(minl, acc[tm][tn][e]);

    float lsum = 0.f;
    if (__any(minl < 2.f)) {
        // ---- exact slow path: full 128-dim Gram + label/triangle-aware scan ----
        f32x4 sqni[4], ti4[4];
        float sqnj[4], tj4[4];
        #pragma unroll
        for (int tm = 0; tm < 4; ++tm) {
            const int i0 = wm * 64 + tm * 16 + quad * 4;
            sqni[tm] = *reinterpret_cast<const f32x4*>(sqn + ibase + i0);
            ti4[tm]  = *reinterpret_cast<const f32x4*>(targets + ibase + i0);
        }
        #pragma unroll
        for (int tn = 0; tn < 4; ++tn) {
            const int jl = wn * 64 + tn * 16 + m15;
            sqnj[tn] = sqn[jbase + jl];
            tj4[tn]  = targets[jbase + jl];
        }
        #pragma unroll
        for (int a = 0; a < 4; ++a)
            #pragma unroll
            for (int b = 0; b < 4; ++b) acc[a][b] = (f32x4){0.f, 0.f, 0.f, 0.f};
        const uint4* fp = reinterpret_cast<const uint4*>(fbf);
        const uint4* base_a = fp + (bi * 8 + wm * 4) * 256 + quad * 16 + m15;
        const uint4* base_b = fp + (bj * 8 + wn * 4) * 256 + quad * 16 + m15;
        #pragma unroll
        for (int ks = 0; ks < 4; ++ks) {
            bf16x8 af[4], bfr[4];
            #pragma unroll
            for (int t = 0; t < 4; ++t) {
                af[t]  = *reinterpret_cast<const bf16x8*>(base_a + t * 256 + ks * 64);
                bfr[t] = *reinterpret_cast<const bf16x8*>(base_b + t * 256 + ks * 64);
            }
            #pragma unroll
            for (int tm = 0; tm < 4; ++tm)
                #pragma unroll
                for (int tn = 0; tn < 4; ++tn)
                    acc[tm][tn] = __builtin_amdgcn_mfma_f32_16x16x32_bf16(
                        af[tm], bfr[tn], acc[tm][tn], 0, 0, 0);
        }
        lsum = (bi == bj)
            ? scan_slow<true >(acc, sqni, ti4, sqnj, tj4, wm, wn, quad, m15)
            : scan_slow<false>(acc, sqni, ti4, sqnj, tj4, wm, wn, quad, m15);
        #pragma unroll
        for (int off = 32; off > 0; off >>= 1) lsum += __shfl_down(lsum, off);
    }
    if (lane == 0) c_part[u * 4 + wv] = lsum;
}

// ================= finalize =====================================================
__global__ __launch_bounds__(256) void finalize_kernel(const float* __restrict__ c_part,
                                                       const float* __restrict__ f_part,
                                                       const float* __restrict__ g_part,
                                                       const float* __restrict__ vpart,
                                                       const float* __restrict__ sqn,
                                                       const float* __restrict__ targets,
                                                       float* __restrict__ out) {
    __shared__ float red[32];
    const int tid = threadIdx.x;
    const int w = tid >> 6, lane = tid & 63;

    float c = 0.f;
    for (int i = tid; i < 8320; i += 256) c += c_part[i];
    float f = (tid < 32) ? f_part[tid] : 0.f;
    float g = g_part[tid];

    float V = 0.f;
    #pragma unroll 8
    for (int b = 0; b < 32; ++b) V += vpart[b * 256 + tid];
    float vsq = V * V;                 // tid<128: class 0; else class 1

    float stot = 0.f, s1 = 0.f, n1 = 0.f;
    for (int i = tid; i < N_PTS; i += 256) {
        const float s = sqn[i], t = targets[i];
        stot += s; s1 += t * s; n1 += t;
    }

    #pragma unroll
    for (int off = 32; off > 0; off >>= 1) {
        c += __shfl_down(c, off);
        f += __shfl_down(f, off);
        g += __shfl_down(g, off);
        vsq  += __shfl_down(vsq, off);
        stot += __shfl_down(stot, off);
        s1   += __shfl_down(s1, off);
        n1   += __shfl_down(n1, off);
    }
    if (lane == 0) {
        red[w] = c; red[4 + w] = f; red[8 + w] = g;
        red[12 + w] = vsq; red[16 + w] = stot; red[20 + w] = s1; red[24 + w] = n1;
    }
    __syncthreads();
    if (tid == 0) {
        const double cs = (double)red[0] + red[1] + red[2] + red[3];
        const double fs = (double)red[4] + red[5] + red[6] + red[7];
        const double gs = (double)red[8] + red[9] + red[10] + red[11];
        const double v0sq = (double)red[12] + red[13];   // waves 0,1 = class 0
        const double v1sq = (double)red[14] + red[15];
        const double st = (double)red[16] + red[17] + red[18] + red[19];
        const double s1s = (double)red[20] + red[21] + red[22] + red[23];
        const double n1s = (double)red[24] + red[25] + red[26] + red[27];
        const double n0s = (double)N_PTS - n1s;
        const double s0s = st - s1s;
        const double same = 2.0 * (n0s * s0s - v0sq) + 2.0 * (n1s * s1s - v1sq);
        out[0] = (float)((cs + same) / ((double)N_PTS * N_PTS)
                         + fs / N_PTS + 0.1 * (gs / (N_PTS - 1)));
    }
}

extern "C" void kernel_launch(void* const* d_in, const int* in_sizes, int n_in,
                              void* d_out, int out_size, void* d_ws, size_t ws_size,
                              hipStream_t stream) {
    const float* preds    = (const float*)d_in[0];
    const float* targets  = (const float*)d_in[1];
    const float* features = (const float*)d_in[2];
    const float* gfeat    = (const float*)d_in[3];
    char* ws = (char*)d_ws;
    __bf16* fbf   = (__bf16*)(ws + FBF_OFF);
    __bf16* ascr  = (__bf16*)(ws + ASCR_OFF);
    __bf16* bscr  = (__bf16*)(ws + BSCR_OFF);
    float* sqn    = (float*)(ws + SQN_OFF);
    float* c_part = (float*)(ws + CPART_OFF);
    float* f_part = (float*)(ws + FPART_OFF);
    float* g_part = (float*)(ws + GPART_OFF);
    float* vpart  = (float*)(ws + VPART_OFF);
    float* out = (float*)d_out;

    aux_kernel<<<832, 256, 0, stream>>>(features, preds, targets, gfeat,
                                        fbf, ascr, bscr, sqn, vpart, f_part, g_part);
    pair_kernel<<<2080, 256, 0, stream>>>(fbf, ascr, bscr, sqn, targets, c_part);
    finalize_kernel<<<1, 256, 0, stream>>>(c_part, f_part, g_part, vpart, sqn, targets, out);
}